// Round 6
// baseline (374.928 us; speedup 1.0000x reference)
//
#include <hip/hip_runtime.h>
#include <stdint.h>

#define S_LEN 4096
#define DMODEL 1024
#define NH 16
#define HDIM 64
#define KSPLIT 2
#define KCHUNK (S_LEN / KSPLIT)

typedef __attribute__((ext_vector_type(8))) __bf16 bf16x8;
typedef __attribute__((ext_vector_type(4))) __bf16 bf16x4;
typedef __attribute__((ext_vector_type(2))) __bf16 bf16x2;
typedef __attribute__((ext_vector_type(4))) float f32x4;
typedef __attribute__((ext_vector_type(16))) float f32x16;
typedef __attribute__((ext_vector_type(4))) unsigned int uint32x4;

// ---------------- f32 -> bf16 pack (vectorized) -------------------------------
__global__ __launch_bounds__(256) void convert_f32_bf16(const float* __restrict__ src,
                                                        __bf16* __restrict__ dst) {
  int idx = blockIdx.x * 256 + threadIdx.x;
  f32x4 v = ((const f32x4*)src)[idx];
  bf16x4 o;
#pragma unroll
  for (int i = 0; i < 4; ++i) o[i] = (__bf16)v[i];
  ((bf16x4*)dst)[idx] = o;
}

// ---------------- tiled transpose (64x64 tiles, batched via z) ----------------
template <typename T>
__global__ __launch_bounds__(256) void transpose_tiles(const T* __restrict__ src,
                                                       __bf16* __restrict__ dst,
                                                       int R, int C) {
  src += (size_t)blockIdx.z * R * C;
  dst += (size_t)blockIdx.z * R * C;
  __shared__ __bf16 tile[64][65];
  const int r0 = blockIdx.y * 64, c0 = blockIdx.x * 64;
  const int t = threadIdx.x;
  const int col = t & 63, rsub = t >> 6;
#pragma unroll
  for (int i = 0; i < 16; ++i) {
    int r = rsub + i * 4;
    tile[r][col] = (__bf16)src[(size_t)(r0 + r) * C + (c0 + col)];
  }
  __syncthreads();
#pragma unroll
  for (int i = 0; i < 16; ++i) {
    int r = rsub + i * 4;
    dst[(size_t)(c0 + r) * R + (r0 + col)] = tile[col][r];
  }
}

// ---------------- GEMM: C = A (M x K) * BT^T, BT is (N x K) row-major ---------
template <int EPI>
__global__ __launch_bounds__(256) void gemm_bt(const __bf16* __restrict__ A,
                                               const __bf16* __restrict__ BT,
                                               __bf16* __restrict__ Cq,
                                               __bf16* __restrict__ Ck,
                                               __bf16* __restrict__ Cv,
                                               float* __restrict__ Cout,
                                               int Kdim, int Ndim) {
  __shared__ __align__(16) __bf16 At[128][40];
  __shared__ __align__(16) __bf16 Bt[128][40];
  const int t = threadIdx.x;
  const int wave = t >> 6, lane = t & 63;
  const int wr = wave >> 1, wc = wave & 1;
  const int lrow = lane & 15, lk = lane >> 4;
  const int bm = blockIdx.x, bn = blockIdx.y;

  f32x4 acc[4][4];
#pragma unroll
  for (int i = 0; i < 4; ++i)
#pragma unroll
    for (int j = 0; j < 4; ++j) acc[i][j] = f32x4{0.f, 0.f, 0.f, 0.f};

  const int arow0 = bm * 128, brow0 = bn * 128;
  for (int k0 = 0; k0 < Kdim; k0 += 32) {
    __syncthreads();
#pragma unroll
    for (int u = 0; u < 2; ++u) {
      int idx = t + u * 256;
      int row = idx >> 2, col = (idx & 3) * 8;
      *(bf16x8*)&At[row][col] =
          *(const bf16x8*)&A[(size_t)(arow0 + row) * Kdim + (k0 + col)];
      *(bf16x8*)&Bt[row][col] =
          *(const bf16x8*)&BT[(size_t)(brow0 + row) * Kdim + (k0 + col)];
    }
    __syncthreads();
    bf16x8 af[4], bfr[4];
#pragma unroll
    for (int mi = 0; mi < 4; ++mi)
      af[mi] = *(const bf16x8*)&At[wr * 64 + mi * 16 + lrow][lk * 8];
#pragma unroll
    for (int ni = 0; ni < 4; ++ni)
      bfr[ni] = *(const bf16x8*)&Bt[wc * 64 + ni * 16 + lrow][lk * 8];
#pragma unroll
    for (int mi = 0; mi < 4; ++mi)
#pragma unroll
      for (int ni = 0; ni < 4; ++ni)
        acc[mi][ni] =
            __builtin_amdgcn_mfma_f32_16x16x32_bf16(af[mi], bfr[ni], acc[mi][ni], 0, 0, 0);
  }

  const int rb = bm * 128 + wr * 64 + lk * 4;
  const int cb = bn * 128 + wc * 64 + lrow;
#pragma unroll
  for (int mi = 0; mi < 4; ++mi)
#pragma unroll
    for (int ni = 0; ni < 4; ++ni) {
      int c = cb + ni * 16;
#pragma unroll
      for (int r = 0; r < 4; ++r) {
        int row = rb + mi * 16 + r;
        float v = acc[mi][ni][r];
        if (EPI == 0) {
          Cout[(size_t)row * Ndim + c] = v;
        } else {
          int type = c >> 10, d = c & 1023;
          int hh = d >> 6, hd = d & 63;
          __bf16* dp = (type == 0) ? Cq : (type == 1) ? Ck : Cv;
          dp[((size_t)hh * S_LEN + row) * HDIM + hd] = (__bf16)v;
        }
      }
    }
}

// ---------------- RoPE in place on (NH, S, HD) Q and K ------------------------
__global__ __launch_bounds__(256) void rope_kernel(__bf16* __restrict__ Q,
                                                   __bf16* __restrict__ Kb,
                                                   const float* __restrict__ freqs) {
  size_t idx = (size_t)blockIdx.x * 256 + threadIdx.x;
  int i = idx & 31;
  size_t rest = idx >> 5;
  int s = rest & 4095;
  int h = (int)(rest >> 12);
  float c = freqs[(s * 32 + i) * 2 + 0];
  float sn = freqs[(s * 32 + i) * 2 + 1];
  size_t base = ((size_t)h * S_LEN + s) * HDIM + 2 * i;
  float qa = (float)Q[base], qb = (float)Q[base + 1];
  Q[base] = (__bf16)(qa * c - qb * sn);
  Q[base + 1] = (__bf16)(qa * sn + qb * c);
  float ka = (float)Kb[base], kb2 = (float)Kb[base + 1];
  Kb[base] = (__bf16)(ka * c - kb2 * sn);
  Kb[base + 1] = (__bf16)(ka * sn + kb2 * c);
}

// ---------------- flash attention, split-K: each block does KCHUNK keys -------
// grid = 32 qb * NH * KSPLIT = 1024 blocks -> 16 waves/CU.
// Writes unnormalized O (f32) + (m,l) per row to workspace; merge kernel combines.
__global__ __launch_bounds__(256, 4) void attn_split_kernel(
    const __bf16* __restrict__ Q, const __bf16* __restrict__ Kmat,
    const __bf16* __restrict__ Vt, const float* __restrict__ mask,
    float* __restrict__ Opart, float* __restrict__ MLpart) {
  __shared__ float maskL[KCHUNK];
  const int t = threadIdx.x;
  const int id = blockIdx.x;                         // 0..1023
  const int swz = (id & 7) * (NH * 32 * KSPLIT / 8) + (id >> 3);  // bijective, 2 heads/XCD
  const int h = swz / (32 * KSPLIT);
  const int rem = swz % (32 * KSPLIT);
  const int qb = rem >> 1;
  const int split = rem & 1;
  const int wave = t >> 6, lane = t & 63;
  const int lq = lane & 31, hi = lane >> 5;
  const int k0 = split * KCHUNK;

  // stage this split's mask-add range (only barrier in the kernel)
#pragma unroll
  for (int i = 0; i < KCHUNK / 256; ++i) {
    int idx = t + i * 256;
    maskL[idx] = (1.0f - mask[k0 + idx]) * -10000.0f;
  }
  __syncthreads();

  // Q fragments (B-operand): lane holds col q = lq, k-dim d = ds*16 + hi*8 + e
  const __bf16* Qh = Q + ((size_t)h * S_LEN + qb * 128 + wave * 32 + lq) * HDIM;
  bf16x8 qf[4];
#pragma unroll
  for (int ds = 0; ds < 4; ++ds) {
    qf[ds] = *(const bf16x8*)(Qh + ds * 16 + hi * 8);
#pragma unroll
    for (int e = 0; e < 8; ++e) qf[ds][e] = (__bf16)((float)qf[ds][e] * 0.125f);
  }

  const __bf16* Kh = Kmat + (size_t)h * S_LEN * HDIM;
  const __bf16* Vh = Vt + (size_t)h * HDIM * S_LEN;

  float m = -1e30f, l = 0.f;
  f32x16 o0, o1;
#pragma unroll
  for (int r = 0; r < 16; ++r) { o0[r] = 0.f; o1[r] = 0.f; }

  // preload first K tile
  bf16x8 kcur[8];
  {
    const __bf16* Kp = Kh + (size_t)(k0 + lq) * HDIM + hi * 8;
#pragma unroll
    for (int ds = 0; ds < 4; ++ds) {
      kcur[ds] = *(const bf16x8*)(Kp + ds * 16);
      kcur[4 + ds] = *(const bf16x8*)(Kp + (size_t)32 * HDIM + ds * 16);
    }
  }

  const int kend = k0 + KCHUNK;
  for (int kb = k0; kb < kend; kb += 64) {
    // ---- QK^T swapped: p[r] = S[k = kb + (r&3)+8*(r>>2)+4*hi][q = lq]
    f32x16 p0, p1;
#pragma unroll
    for (int r = 0; r < 16; ++r) { p0[r] = 0.f; p1[r] = 0.f; }
#pragma unroll
    for (int ds = 0; ds < 4; ++ds)
      p0 = __builtin_amdgcn_mfma_f32_32x32x16_bf16(kcur[ds], qf[ds], p0, 0, 0, 0);
#pragma unroll
    for (int ds = 0; ds < 4; ++ds)
      p1 = __builtin_amdgcn_mfma_f32_32x32x16_bf16(kcur[4 + ds], qf[ds], p1, 0, 0, 0);

    // ---- prefetch next K tile (after QK^T so kcur/knext don't co-live long);
    // last iteration wraps to k0 (harmless, values unused)
    bf16x8 knext[8];
    {
      int kn = (kb + 64 < kend) ? kb + 64 : k0;
      const __bf16* Kpn = Kh + (size_t)(kn + lq) * HDIM + hi * 8;
#pragma unroll
      for (int ds = 0; ds < 4; ++ds) {
        knext[ds] = *(const bf16x8*)(Kpn + ds * 16);
        knext[4 + ds] = *(const bf16x8*)(Kpn + (size_t)32 * HDIM + ds * 16);
      }
    }

    // ---- mask add (broadcast f32x4 LDS reads)
    const int kk = kb - k0;
#pragma unroll
    for (int tq = 0; tq < 4; ++tq) {
      f32x4 ma0 = *(const f32x4*)&maskL[kk + tq * 8 + hi * 4];
      f32x4 ma1 = *(const f32x4*)&maskL[kk + 32 + tq * 8 + hi * 4];
#pragma unroll
      for (int c = 0; c < 4; ++c) {
        p0[tq * 4 + c] += ma0[c];
        p1[tq * 4 + c] += ma1[c];
      }
    }

    // ---- online softmax: per-lane over 32 vals + one xor-32 shuffle each
    float mx = p0[0];
#pragma unroll
    for (int r = 1; r < 16; ++r) mx = fmaxf(mx, p0[r]);
#pragma unroll
    for (int r = 0; r < 16; ++r) mx = fmaxf(mx, p1[r]);
    mx = fmaxf(mx, __shfl_xor(mx, 32));
    float mn = fmaxf(m, mx);
    float alpha = exp2f((m - mn) * 1.44269504f);
    m = mn;
    float ps = 0.f;
#pragma unroll
    for (int r = 0; r < 16; ++r) {
      float pe = exp2f((p0[r] - mn) * 1.44269504f);
      p0[r] = pe;
      ps += pe;
    }
#pragma unroll
    for (int r = 0; r < 16; ++r) {
      float pe = exp2f((p1[r] - mn) * 1.44269504f);
      p1[r] = pe;
      ps += pe;
    }
    ps += __shfl_xor(ps, 32);
    l = l * alpha + ps;
#pragma unroll
    for (int r = 0; r < 16; ++r) { o0[r] *= alpha; o1[r] *= alpha; }

    // ---- pack P to bf16 pairs: tt[tp] holds k = 8*(tp>>1) + 4*hi + (2tp&3)+{0,1}
    unsigned int tt0[8], tt1[8];
#pragma unroll
    for (int tp = 0; tp < 8; ++tp) {
      bf16x2 w0, w1;
      w0[0] = (__bf16)p0[2 * tp]; w0[1] = (__bf16)p0[2 * tp + 1];
      w1[0] = (__bf16)p1[2 * tp]; w1[1] = (__bf16)p1[2 * tp + 1];
      tt0[tp] = __builtin_bit_cast(unsigned int, w0);
      tt1[tp] = __builtin_bit_cast(unsigned int, w1);
    }

    // ---- build PV B-fragments via shfl_xor(32) + select (verified round 5)
#pragma unroll
    for (int ks = 0; ks < 4; ++ks) {
      unsigned int b0, b1, b2, b3;
      if (ks == 0)      { b0 = tt0[0]; b1 = tt0[1]; b2 = tt0[2]; b3 = tt0[3]; }
      else if (ks == 1) { b0 = tt0[4]; b1 = tt0[5]; b2 = tt0[6]; b3 = tt0[7]; }
      else if (ks == 2) { b0 = tt1[0]; b1 = tt1[1]; b2 = tt1[2]; b3 = tt1[3]; }
      else              { b0 = tt1[4]; b1 = tt1[5]; b2 = tt1[6]; b3 = tt1[7]; }
      unsigned int x0 = (unsigned int)__shfl_xor((int)b0, 32);
      unsigned int x1 = (unsigned int)__shfl_xor((int)b1, 32);
      unsigned int x2 = (unsigned int)__shfl_xor((int)b2, 32);
      unsigned int x3 = (unsigned int)__shfl_xor((int)b3, 32);
      uint32x4 pb;
      pb[0] = hi ? x2 : b0;
      pb[1] = hi ? x3 : b1;
      pb[2] = hi ? b2 : x0;
      pb[3] = hi ? b3 : x1;
      bf16x8 pbv = __builtin_bit_cast(bf16x8, pb);
      bf16x8 v0 = *(const bf16x8*)(Vh + (size_t)(0 + lq) * S_LEN + kb + ks * 16 + hi * 8);
      bf16x8 v1 = *(const bf16x8*)(Vh + (size_t)(32 + lq) * S_LEN + kb + ks * 16 + hi * 8);
      o0 = __builtin_amdgcn_mfma_f32_32x32x16_bf16(v0, pbv, o0, 0, 0, 0);
      o1 = __builtin_amdgcn_mfma_f32_32x32x16_bf16(v1, pbv, o1, 0, 0, 0);
    }

#pragma unroll
    for (int i = 0; i < 8; ++i) kcur[i] = knext[i];
  }

  // ---- epilogue: store UNNORMALIZED partial O (f32) and (m, l)
  const int qrow = qb * 128 + wave * 32 + lq;
  float* Op = Opart + (((size_t)split * NH + h) * S_LEN + qrow) * 64;
#pragma unroll
  for (int tq = 0; tq < 4; ++tq) {
    f32x4 a, b;
#pragma unroll
    for (int c = 0; c < 4; ++c) { a[c] = o0[tq * 4 + c]; b[c] = o1[tq * 4 + c]; }
    *(f32x4*)(Op + tq * 8 + hi * 4) = a;
    *(f32x4*)(Op + 32 + tq * 8 + hi * 4) = b;
  }
  if (hi == 0) {
    size_t mlidx = (((size_t)split * NH + h) * S_LEN + qrow) * 2;
    MLpart[mlidx] = m;
    MLpart[mlidx + 1] = l;
  }
}

// ---------------- merge the KSPLIT partials -> AO (bf16) ----------------------
__global__ __launch_bounds__(256) void attn_merge(const float* __restrict__ Opart,
                                                  const float* __restrict__ MLpart,
                                                  __bf16* __restrict__ AO) {
  int idx = blockIdx.x * 256 + threadIdx.x;  // NH*S*16 threads
  int dd = (idx & 15) * 4;
  int hq = idx >> 4;                          // h*S + q
  int q = hq & (S_LEN - 1), h = hq >> 12;
  float m0 = MLpart[(size_t)hq * 2], l0 = MLpart[(size_t)hq * 2 + 1];
  float m1 = MLpart[((size_t)NH * S_LEN + hq) * 2], l1 = MLpart[((size_t)NH * S_LEN + hq) * 2 + 1];
  float M = fmaxf(m0, m1);
  float w0 = exp2f((m0 - M) * 1.44269504f);
  float w1 = exp2f((m1 - M) * 1.44269504f);
  float inv = 1.0f / fmaxf(l0 * w0 + l1 * w1, 1e-30f);
  f32x4 a = *(const f32x4*)&Opart[(size_t)hq * 64 + dd];
  f32x4 b = *(const f32x4*)&Opart[((size_t)NH * S_LEN + hq) * 64 + dd];
  bf16x4 o;
#pragma unroll
  for (int c = 0; c < 4; ++c) o[c] = (__bf16)((a[c] * w0 + b[c] * w1) * inv);
  *(bf16x4*)&AO[(size_t)q * DMODEL + h * HDIM + dd] = o;
}

// ---------------- round-5 single-pass attention (fallback if ws too small) ----
__global__ __launch_bounds__(256, 2) void attn_kernel_full(const __bf16* __restrict__ Q,
                                                           const __bf16* __restrict__ Kmat,
                                                           const __bf16* __restrict__ Vt,
                                                           const float* __restrict__ mask,
                                                           __bf16* __restrict__ AO) {
  __shared__ float maskL[S_LEN];
  const int t = threadIdx.x;
  const int id = blockIdx.x;
  const int swz = (id & 7) * 64 + (id >> 3);
  const int h = swz >> 5;
  const int qb = swz & 31;
  const int wave = t >> 6, lane = t & 63;
  const int lq = lane & 31, hi = lane >> 5;

#pragma unroll
  for (int i = 0; i < 16; ++i) {
    int idx = t + i * 256;
    maskL[idx] = (1.0f - mask[idx]) * -10000.0f;
  }
  __syncthreads();

  const __bf16* Qh = Q + ((size_t)h * S_LEN + qb * 128 + wave * 32 + lq) * HDIM;
  bf16x8 qf[4];
#pragma unroll
  for (int ds = 0; ds < 4; ++ds) {
    qf[ds] = *(const bf16x8*)(Qh + ds * 16 + hi * 8);
#pragma unroll
    for (int e = 0; e < 8; ++e) qf[ds][e] = (__bf16)((float)qf[ds][e] * 0.125f);
  }

  const __bf16* Kh = Kmat + (size_t)h * S_LEN * HDIM;
  const __bf16* Vh = Vt + (size_t)h * HDIM * S_LEN;

  float m = -1e30f, l = 0.f;
  f32x16 o0, o1;
#pragma unroll
  for (int r = 0; r < 16; ++r) { o0[r] = 0.f; o1[r] = 0.f; }

  for (int kb = 0; kb < S_LEN; kb += 64) {
    f32x16 p0, p1;
#pragma unroll
    for (int r = 0; r < 16; ++r) { p0[r] = 0.f; p1[r] = 0.f; }
#pragma unroll
    for (int ds = 0; ds < 4; ++ds) {
      bf16x8 kf0 = *(const bf16x8*)(Kh + (size_t)(kb + lq) * HDIM + ds * 16 + hi * 8);
      p0 = __builtin_amdgcn_mfma_f32_32x32x16_bf16(kf0, qf[ds], p0, 0, 0, 0);
    }
#pragma unroll
    for (int ds = 0; ds < 4; ++ds) {
      bf16x8 kf1 = *(const bf16x8*)(Kh + (size_t)(kb + 32 + lq) * HDIM + ds * 16 + hi * 8);
      p1 = __builtin_amdgcn_mfma_f32_32x32x16_bf16(kf1, qf[ds], p1, 0, 0, 0);
    }
#pragma unroll
    for (int tq = 0; tq < 4; ++tq) {
      f32x4 ma0 = *(const f32x4*)&maskL[kb + tq * 8 + hi * 4];
      f32x4 ma1 = *(const f32x4*)&maskL[kb + 32 + tq * 8 + hi * 4];
#pragma unroll
      for (int c = 0; c < 4; ++c) {
        p0[tq * 4 + c] += ma0[c];
        p1[tq * 4 + c] += ma1[c];
      }
    }
    float mx = p0[0];
#pragma unroll
    for (int r = 1; r < 16; ++r) mx = fmaxf(mx, p0[r]);
#pragma unroll
    for (int r = 0; r < 16; ++r) mx = fmaxf(mx, p1[r]);
    mx = fmaxf(mx, __shfl_xor(mx, 32));
    float mn = fmaxf(m, mx);
    float alpha = exp2f((m - mn) * 1.44269504f);
    m = mn;
    float ps = 0.f;
#pragma unroll
    for (int r = 0; r < 16; ++r) {
      float pe = exp2f((p0[r] - mn) * 1.44269504f);
      p0[r] = pe;
      ps += pe;
    }
#pragma unroll
    for (int r = 0; r < 16; ++r) {
      float pe = exp2f((p1[r] - mn) * 1.44269504f);
      p1[r] = pe;
      ps += pe;
    }
    ps += __shfl_xor(ps, 32);
    l = l * alpha + ps;
#pragma unroll
    for (int r = 0; r < 16; ++r) { o0[r] *= alpha; o1[r] *= alpha; }

    unsigned int tt0[8], tt1[8];
#pragma unroll
    for (int tp = 0; tp < 8; ++tp) {
      bf16x2 w0, w1;
      w0[0] = (__bf16)p0[2 * tp]; w0[1] = (__bf16)p0[2 * tp + 1];
      w1[0] = (__bf16)p1[2 * tp]; w1[1] = (__bf16)p1[2 * tp + 1];
      tt0[tp] = __builtin_bit_cast(unsigned int, w0);
      tt1[tp] = __builtin_bit_cast(unsigned int, w1);
    }
#pragma unroll
    for (int ks = 0; ks < 4; ++ks) {
      unsigned int b0, b1, b2, b3;
      if (ks == 0)      { b0 = tt0[0]; b1 = tt0[1]; b2 = tt0[2]; b3 = tt0[3]; }
      else if (ks == 1) { b0 = tt0[4]; b1 = tt0[5]; b2 = tt0[6]; b3 = tt0[7]; }
      else if (ks == 2) { b0 = tt1[0]; b1 = tt1[1]; b2 = tt1[2]; b3 = tt1[3]; }
      else              { b0 = tt1[4]; b1 = tt1[5]; b2 = tt1[6]; b3 = tt1[7]; }
      unsigned int x0 = (unsigned int)__shfl_xor((int)b0, 32);
      unsigned int x1 = (unsigned int)__shfl_xor((int)b1, 32);
      unsigned int x2 = (unsigned int)__shfl_xor((int)b2, 32);
      unsigned int x3 = (unsigned int)__shfl_xor((int)b3, 32);
      uint32x4 pb;
      pb[0] = hi ? x2 : b0;
      pb[1] = hi ? x3 : b1;
      pb[2] = hi ? b2 : x0;
      pb[3] = hi ? b3 : x1;
      bf16x8 pbv = __builtin_bit_cast(bf16x8, pb);
      bf16x8 v0 = *(const bf16x8*)(Vh + (size_t)(0 + lq) * S_LEN + kb + ks * 16 + hi * 8);
      bf16x8 v1 = *(const bf16x8*)(Vh + (size_t)(32 + lq) * S_LEN + kb + ks * 16 + hi * 8);
      o0 = __builtin_amdgcn_mfma_f32_32x32x16_bf16(v0, pbv, o0, 0, 0, 0);
      o1 = __builtin_amdgcn_mfma_f32_32x32x16_bf16(v1, pbv, o1, 0, 0, 0);
    }
  }

  float inv = 1.0f / fmaxf(l, 1e-30f);
  __bf16* aorow = AO + (size_t)(qb * 128 + wave * 32 + lq) * DMODEL + h * HDIM;
#pragma unroll
  for (int tq = 0; tq < 4; ++tq) {
    bf16x4 ov0, ov1;
#pragma unroll
    for (int c = 0; c < 4; ++c) {
      ov0[c] = (__bf16)(o0[tq * 4 + c] * inv);
      ov1[c] = (__bf16)(o1[tq * 4 + c] * inv);
    }
    *(bf16x4*)(aorow + tq * 8 + hi * 4) = ov0;
    *(bf16x4*)(aorow + 32 + tq * 8 + hi * 4) = ov1;
  }
}

// ------------------------------------------------------------------------------
extern "C" void kernel_launch(void* const* d_in, const int* in_sizes, int n_in,
                              void* d_out, int out_size, void* d_ws, size_t ws_size,
                              hipStream_t stream) {
  const float* X = (const float*)d_in[0];
  const float* freqs = (const float*)d_in[1];
  const float* mask = (const float*)d_in[2];
  const float* wq = (const float*)d_in[3];
  const float* wk = (const float*)d_in[4];
  const float* wv = (const float*)d_in[5];
  const float* wo = (const float*)d_in[6];
  float* out = (float*)d_out;

  __bf16* WTqkv = (__bf16*)d_ws;                       // 3072*1024
  __bf16* WoT = WTqkv + 3072 * 1024;                   // 1024*1024
  __bf16* Xb = WoT + 1024 * 1024;                      // 4096*1024
  __bf16* Qb = Xb + (size_t)S_LEN * DMODEL;
  __bf16* Kb = Qb + (size_t)NH * S_LEN * HDIM;
  __bf16* Vb = Kb + (size_t)NH * S_LEN * HDIM;
  __bf16* Vtb = Vb + (size_t)NH * S_LEN * HDIM;
  __bf16* AO = Vb;  // V raw is dead after V->Vt transpose

  float* Opart = (float*)(Vtb + (size_t)NH * S_LEN * HDIM);
  float* MLpart = Opart + (size_t)KSPLIT * NH * S_LEN * 64;
  size_t ws_needed = (size_t)((char*)(MLpart + (size_t)KSPLIT * NH * S_LEN * 2) - (char*)d_ws);

  convert_f32_bf16<<<dim3(S_LEN * DMODEL / 1024), 256, 0, stream>>>(X, Xb);

  transpose_tiles<float><<<dim3(16, 16, 1), 256, 0, stream>>>(wq, WTqkv, 1024, 1024);
  transpose_tiles<float><<<dim3(16, 16, 1), 256, 0, stream>>>(wk, WTqkv + 1024 * 1024, 1024, 1024);
  transpose_tiles<float><<<dim3(16, 16, 1), 256, 0, stream>>>(wv, WTqkv + 2 * 1024 * 1024, 1024, 1024);
  transpose_tiles<float><<<dim3(16, 16, 1), 256, 0, stream>>>(wo, WoT, 1024, 1024);

  gemm_bt<1><<<dim3(32, 24), 256, 0, stream>>>(Xb, WTqkv, Qb, Kb, Vb, nullptr, 1024, 3072);

  rope_kernel<<<dim3((NH * S_LEN * 32) / 256), 256, 0, stream>>>(Qb, Kb, freqs);

  transpose_tiles<__bf16><<<dim3(1, 64, NH), 256, 0, stream>>>(Vb, Vtb, S_LEN, HDIM);

  if (ws_size >= ws_needed) {
    attn_split_kernel<<<dim3(32 * NH * KSPLIT), 256, 0, stream>>>(Qb, Kb, Vtb, mask, Opart, MLpart);
    attn_merge<<<dim3(NH * S_LEN * 16 / 256), 256, 0, stream>>>(Opart, MLpart, AO);
  } else {
    attn_kernel_full<<<dim3(512), 256, 0, stream>>>(Qb, Kb, Vtb, mask, AO);
  }

  gemm_bt<0><<<dim3(32, 8), 256, 0, stream>>>(AO, WoT, nullptr, nullptr, nullptr, out, 1024, 1024);
}

// Round 7
// 329.928 us; speedup vs baseline: 1.1364x; 1.1364x over previous
//
#include <hip/hip_runtime.h>
#include <stdint.h>

#define S_LEN 4096
#define DMODEL 1024
#define NH 16
#define HDIM 64
#define LOG2E 1.44269504088896340736f

typedef __attribute__((ext_vector_type(8))) __bf16 bf16x8;
typedef __attribute__((ext_vector_type(4))) __bf16 bf16x4;
typedef __attribute__((ext_vector_type(2))) __bf16 bf16x2;
typedef __attribute__((ext_vector_type(4))) float f32x4;
typedef __attribute__((ext_vector_type(16))) float f32x16;
typedef __attribute__((ext_vector_type(4))) unsigned int uint32x4;

// ---------------- f32 -> bf16 pack (vectorized) -------------------------------
__global__ __launch_bounds__(256) void convert_f32_bf16(const float* __restrict__ src,
                                                        __bf16* __restrict__ dst) {
  int idx = blockIdx.x * 256 + threadIdx.x;
  f32x4 v = ((const f32x4*)src)[idx];
  bf16x4 o;
#pragma unroll
  for (int i = 0; i < 4; ++i) o[i] = (__bf16)v[i];
  ((bf16x4*)dst)[idx] = o;
}

// ---------------- tiled transpose (64x64 tiles, batched via z) ----------------
template <typename T>
__global__ __launch_bounds__(256) void transpose_tiles(const T* __restrict__ src,
                                                       __bf16* __restrict__ dst,
                                                       int R, int C) {
  src += (size_t)blockIdx.z * R * C;
  dst += (size_t)blockIdx.z * R * C;
  __shared__ __bf16 tile[64][65];
  const int r0 = blockIdx.y * 64, c0 = blockIdx.x * 64;
  const int t = threadIdx.x;
  const int col = t & 63, rsub = t >> 6;
#pragma unroll
  for (int i = 0; i < 16; ++i) {
    int r = rsub + i * 4;
    tile[r][col] = (__bf16)src[(size_t)(r0 + r) * C + (c0 + col)];
  }
  __syncthreads();
#pragma unroll
  for (int i = 0; i < 16; ++i) {
    int r = rsub + i * 4;
    dst[(size_t)(c0 + r) * R + (r0 + col)] = tile[col][r];
  }
}

// ---------------- GEMM: C = A (M x K) * BT^T, BT is (N x K) row-major ---------
template <int EPI>
__global__ __launch_bounds__(256) void gemm_bt(const __bf16* __restrict__ A,
                                               const __bf16* __restrict__ BT,
                                               __bf16* __restrict__ Cq,
                                               __bf16* __restrict__ Ck,
                                               __bf16* __restrict__ Cv,
                                               float* __restrict__ Cout,
                                               int Kdim, int Ndim) {
  __shared__ __align__(16) __bf16 At[128][40];
  __shared__ __align__(16) __bf16 Bt[128][40];
  const int t = threadIdx.x;
  const int wave = t >> 6, lane = t & 63;
  const int wr = wave >> 1, wc = wave & 1;
  const int lrow = lane & 15, lk = lane >> 4;
  const int bm = blockIdx.x, bn = blockIdx.y;

  f32x4 acc[4][4];
#pragma unroll
  for (int i = 0; i < 4; ++i)
#pragma unroll
    for (int j = 0; j < 4; ++j) acc[i][j] = f32x4{0.f, 0.f, 0.f, 0.f};

  const int arow0 = bm * 128, brow0 = bn * 128;
  for (int k0 = 0; k0 < Kdim; k0 += 32) {
    __syncthreads();
#pragma unroll
    for (int u = 0; u < 2; ++u) {
      int idx = t + u * 256;
      int row = idx >> 2, col = (idx & 3) * 8;
      *(bf16x8*)&At[row][col] =
          *(const bf16x8*)&A[(size_t)(arow0 + row) * Kdim + (k0 + col)];
      *(bf16x8*)&Bt[row][col] =
          *(const bf16x8*)&BT[(size_t)(brow0 + row) * Kdim + (k0 + col)];
    }
    __syncthreads();
    bf16x8 af[4], bfr[4];
#pragma unroll
    for (int mi = 0; mi < 4; ++mi)
      af[mi] = *(const bf16x8*)&At[wr * 64 + mi * 16 + lrow][lk * 8];
#pragma unroll
    for (int ni = 0; ni < 4; ++ni)
      bfr[ni] = *(const bf16x8*)&Bt[wc * 64 + ni * 16 + lrow][lk * 8];
#pragma unroll
    for (int mi = 0; mi < 4; ++mi)
#pragma unroll
      for (int ni = 0; ni < 4; ++ni)
        acc[mi][ni] =
            __builtin_amdgcn_mfma_f32_16x16x32_bf16(af[mi], bfr[ni], acc[mi][ni], 0, 0, 0);
  }

  const int rb = bm * 128 + wr * 64 + lk * 4;
  const int cb = bn * 128 + wc * 64 + lrow;
#pragma unroll
  for (int mi = 0; mi < 4; ++mi)
#pragma unroll
    for (int ni = 0; ni < 4; ++ni) {
      int c = cb + ni * 16;
#pragma unroll
      for (int r = 0; r < 4; ++r) {
        int row = rb + mi * 16 + r;
        float v = acc[mi][ni][r];
        if (EPI == 0) {
          Cout[(size_t)row * Ndim + c] = v;
        } else {
          int type = c >> 10, d = c & 1023;
          int hh = d >> 6, hd = d & 63;
          __bf16* dp = (type == 0) ? Cq : (type == 1) ? Ck : Cv;
          dp[((size_t)hh * S_LEN + row) * HDIM + hd] = (__bf16)v;
        }
      }
    }
}

// ---------------- RoPE in place on (NH, S, HD) Q and K ------------------------
__global__ __launch_bounds__(256) void rope_kernel(__bf16* __restrict__ Q,
                                                   __bf16* __restrict__ Kb,
                                                   const float* __restrict__ freqs) {
  size_t idx = (size_t)blockIdx.x * 256 + threadIdx.x;
  int i = idx & 31;
  size_t rest = idx >> 5;
  int s = rest & 4095;
  int h = (int)(rest >> 12);
  float c = freqs[(s * 32 + i) * 2 + 0];
  float sn = freqs[(s * 32 + i) * 2 + 1];
  size_t base = ((size_t)h * S_LEN + s) * HDIM + 2 * i;
  float qa = (float)Q[base], qb = (float)Q[base + 1];
  Q[base] = (__bf16)(qa * c - qb * sn);
  Q[base + 1] = (__bf16)(qa * sn + qb * c);
  float ka = (float)Kb[base], kb2 = (float)Kb[base + 1];
  Kb[base] = (__bf16)(ka * c - kb2 * sn);
  Kb[base + 1] = (__bf16)(ka * sn + kb2 * c);
}

// ---------------- flash attention: swapped-QK^T, 32x32x16, latency-pipelined --
// 512 blocks (32 qb x 16 heads), 4 waves x 32 q-rows. Per 64-key tile:
// QK^T(kcur) -> V-load hoist -> K-prefetch(knext, no copies via 2x unroll)
// -> fused scale+mask FMA (log2 domain) -> tree softmax + defer-rescale -> PV.
__global__ __launch_bounds__(256, 2) void attn_kernel(const __bf16* __restrict__ Q,
                                                      const __bf16* __restrict__ Kmat,
                                                      const __bf16* __restrict__ Vt,
                                                      const float* __restrict__ mask,
                                                      __bf16* __restrict__ AO) {
  __shared__ float maskL[S_LEN];
  const int t = threadIdx.x;
  const int id = blockIdx.x;                    // 0..511
  const int swz = (id & 7) * 64 + (id >> 3);    // 512 = 8*64: bijective
  const int h = swz >> 5;
  const int qb = swz & 31;
  const int wave = t >> 6, lane = t & 63;
  const int lq = lane & 31, hi = lane >> 5;

  // stage mask in log2 domain (only barrier in the kernel)
#pragma unroll
  for (int i = 0; i < 16; ++i) {
    int idx = t + i * 256;
    maskL[idx] = (1.0f - mask[idx]) * (-10000.0f * LOG2E);
  }
  __syncthreads();

  // Q fragments (B-operand), UNSCALED (scale folded into the post-MFMA FMA)
  const __bf16* Qh = Q + ((size_t)h * S_LEN + qb * 128 + wave * 32 + lq) * HDIM;
  bf16x8 qf[4];
#pragma unroll
  for (int ds = 0; ds < 4; ++ds) qf[ds] = *(const bf16x8*)(Qh + ds * 16 + hi * 8);

  const __bf16* Kh = Kmat + (size_t)h * S_LEN * HDIM;
  const __bf16* Vh = Vt + (size_t)h * HDIM * S_LEN;
  const float SCL = 0.125f * LOG2E;

  float m = -1e30f, l = 0.f;
  f32x16 o0, o1;
#pragma unroll
  for (int r = 0; r < 16; ++r) { o0[r] = 0.f; o1[r] = 0.f; }

  auto load_k = [&](bf16x8(&kr)[8], int kbase) {
    const __bf16* Kp = Kh + (size_t)(kbase + lq) * HDIM + hi * 8;
#pragma unroll
    for (int ds = 0; ds < 4; ++ds) {
      kr[ds] = *(const bf16x8*)(Kp + ds * 16);
      kr[4 + ds] = *(const bf16x8*)(Kp + 32 * HDIM + ds * 16);
    }
  };

  auto tile = [&](const bf16x8(&kc)[8], bf16x8(&kn)[8], int kb, int knb) {
    // ---- QK^T swapped: p[r] = S_raw[k = kb + (r&3)+8*(r>>2)+4*hi][q = lq]
    f32x16 p0, p1;
#pragma unroll
    for (int r = 0; r < 16; ++r) { p0[r] = 0.f; p1[r] = 0.f; }
#pragma unroll
    for (int ds = 0; ds < 4; ++ds)
      p0 = __builtin_amdgcn_mfma_f32_32x32x16_bf16(kc[ds], qf[ds], p0, 0, 0, 0);
#pragma unroll
    for (int ds = 0; ds < 4; ++ds)
      p1 = __builtin_amdgcn_mfma_f32_32x32x16_bf16(kc[4 + ds], qf[ds], p1, 0, 0, 0);

    // ---- hoist ALL V loads for this tile (independent of QK^T results)
    bf16x8 vv[8];
    {
      const __bf16* Vp = Vh + (size_t)lq * S_LEN + kb + hi * 8;
#pragma unroll
      for (int ks = 0; ks < 4; ++ks) {
        vv[ks] = *(const bf16x8*)(Vp + ks * 16);
        vv[4 + ks] = *(const bf16x8*)(Vp + 32 * S_LEN + ks * 16);
      }
    }
    // ---- prefetch next K tile (latency hides under softmax+PV)
    load_k(kn, knb);

    // ---- fused scale+mask: p = S_raw*(0.125*log2e) + mask_log2
    const int kk = kb;
#pragma unroll
    for (int tq = 0; tq < 4; ++tq) {
      f32x4 ma0 = *(const f32x4*)&maskL[kk + tq * 8 + hi * 4];
      f32x4 ma1 = *(const f32x4*)&maskL[kk + 32 + tq * 8 + hi * 4];
#pragma unroll
      for (int c = 0; c < 4; ++c) {
        p0[tq * 4 + c] = fmaf(p0[tq * 4 + c], SCL, ma0[c]);
        p1[tq * 4 + c] = fmaf(p1[tq * 4 + c], SCL, ma1[c]);
      }
    }

    // ---- tree max over 32 vals + one xor-32 shuffle
    float mA, mB;
    {
      float u0 = fmaxf(fmaxf(p0[0], p0[1]), fmaxf(p0[2], p0[3]));
      float u1 = fmaxf(fmaxf(p0[4], p0[5]), fmaxf(p0[6], p0[7]));
      float u2 = fmaxf(fmaxf(p0[8], p0[9]), fmaxf(p0[10], p0[11]));
      float u3 = fmaxf(fmaxf(p0[12], p0[13]), fmaxf(p0[14], p0[15]));
      mA = fmaxf(fmaxf(u0, u1), fmaxf(u2, u3));
      float w0 = fmaxf(fmaxf(p1[0], p1[1]), fmaxf(p1[2], p1[3]));
      float w1 = fmaxf(fmaxf(p1[4], p1[5]), fmaxf(p1[6], p1[7]));
      float w2 = fmaxf(fmaxf(p1[8], p1[9]), fmaxf(p1[10], p1[11]));
      float w3 = fmaxf(fmaxf(p1[12], p1[13]), fmaxf(p1[14], p1[15]));
      mB = fmaxf(fmaxf(w0, w1), fmaxf(w2, w3));
    }
    float mx = fmaxf(mA, mB);
    mx = fmaxf(mx, __shfl_xor(mx, 32));

    // ---- defer-rescale (THR=0: skip when alpha == 1 exactly)
    if (!__all(mx <= m)) {
      float mn = fmaxf(m, mx);
      float al = exp2f(m - mn);
      m = mn;
      l *= al;
#pragma unroll
      for (int r = 0; r < 16; ++r) { o0[r] *= al; o1[r] *= al; }
    }

    // ---- exp (log2 domain) + tree sum
#pragma unroll
    for (int r = 0; r < 16; ++r) p0[r] = exp2f(p0[r] - m);
#pragma unroll
    for (int r = 0; r < 16; ++r) p1[r] = exp2f(p1[r] - m);
    {
      float a0 = (p0[0] + p0[1]) + (p0[2] + p0[3]);
      float a1 = (p0[4] + p0[5]) + (p0[6] + p0[7]);
      float a2 = (p0[8] + p0[9]) + (p0[10] + p0[11]);
      float a3 = (p0[12] + p0[13]) + (p0[14] + p0[15]);
      float b0 = (p1[0] + p1[1]) + (p1[2] + p1[3]);
      float b1 = (p1[4] + p1[5]) + (p1[6] + p1[7]);
      float b2 = (p1[8] + p1[9]) + (p1[10] + p1[11]);
      float b3 = (p1[12] + p1[13]) + (p1[14] + p1[15]);
      float ps = ((a0 + a1) + (a2 + a3)) + ((b0 + b1) + (b2 + b3));
      ps += __shfl_xor(ps, 32);
      l += ps;
    }

    // ---- pack P to bf16 pairs: tt[tp] holds k = 8*(tp>>1) + 4*hi + (2tp&3)+{0,1}
    unsigned int tt0[8], tt1[8];
#pragma unroll
    for (int tp = 0; tp < 8; ++tp) {
      bf16x2 w0, w1;
      w0[0] = (__bf16)p0[2 * tp]; w0[1] = (__bf16)p0[2 * tp + 1];
      w1[0] = (__bf16)p1[2 * tp]; w1[1] = (__bf16)p1[2 * tp + 1];
      tt0[tp] = __builtin_bit_cast(unsigned int, w0);
      tt1[tp] = __builtin_bit_cast(unsigned int, w1);
    }

    // ---- build PV B-fragments via shfl_xor(32) + select (verified round 5)
#pragma unroll
    for (int ks = 0; ks < 4; ++ks) {
      unsigned int b0, b1, b2, b3;
      if (ks == 0)      { b0 = tt0[0]; b1 = tt0[1]; b2 = tt0[2]; b3 = tt0[3]; }
      else if (ks == 1) { b0 = tt0[4]; b1 = tt0[5]; b2 = tt0[6]; b3 = tt0[7]; }
      else if (ks == 2) { b0 = tt1[0]; b1 = tt1[1]; b2 = tt1[2]; b3 = tt1[3]; }
      else              { b0 = tt1[4]; b1 = tt1[5]; b2 = tt1[6]; b3 = tt1[7]; }
      unsigned int x0 = (unsigned int)__shfl_xor((int)b0, 32);
      unsigned int x1 = (unsigned int)__shfl_xor((int)b1, 32);
      unsigned int x2 = (unsigned int)__shfl_xor((int)b2, 32);
      unsigned int x3 = (unsigned int)__shfl_xor((int)b3, 32);
      uint32x4 pb;
      pb[0] = hi ? x2 : b0;
      pb[1] = hi ? x3 : b1;
      pb[2] = hi ? b2 : x0;
      pb[3] = hi ? b3 : x1;
      bf16x8 pbv = __builtin_bit_cast(bf16x8, pb);
      o0 = __builtin_amdgcn_mfma_f32_32x32x16_bf16(vv[ks], pbv, o0, 0, 0, 0);
      o1 = __builtin_amdgcn_mfma_f32_32x32x16_bf16(vv[4 + ks], pbv, o1, 0, 0, 0);
    }
  };

  bf16x8 kA[8], kB[8];
  load_k(kA, 0);
  for (int kb = 0; kb < S_LEN; kb += 128) {
    tile(kA, kB, kb, kb + 64);
    tile(kB, kA, kb + 64, (kb + 128) & (S_LEN - 1));  // last prefetch wraps, unused
  }

  // ---- epilogue: normalize and store; d = 8*tq + 4*hi + c, q = lq
  float inv = 1.0f / fmaxf(l, 1e-30f);
  __bf16* aorow = AO + (size_t)(qb * 128 + wave * 32 + lq) * DMODEL + h * HDIM;
#pragma unroll
  for (int tq = 0; tq < 4; ++tq) {
    bf16x4 ov0, ov1;
#pragma unroll
    for (int c = 0; c < 4; ++c) {
      ov0[c] = (__bf16)(o0[tq * 4 + c] * inv);
      ov1[c] = (__bf16)(o1[tq * 4 + c] * inv);
    }
    *(bf16x4*)(aorow + tq * 8 + hi * 4) = ov0;
    *(bf16x4*)(aorow + 32 + tq * 8 + hi * 4) = ov1;
  }
}

// ------------------------------------------------------------------------------
extern "C" void kernel_launch(void* const* d_in, const int* in_sizes, int n_in,
                              void* d_out, int out_size, void* d_ws, size_t ws_size,
                              hipStream_t stream) {
  const float* X = (const float*)d_in[0];
  const float* freqs = (const float*)d_in[1];
  const float* mask = (const float*)d_in[2];
  const float* wq = (const float*)d_in[3];
  const float* wk = (const float*)d_in[4];
  const float* wv = (const float*)d_in[5];
  const float* wo = (const float*)d_in[6];
  float* out = (float*)d_out;

  __bf16* WTqkv = (__bf16*)d_ws;                       // 3072*1024
  __bf16* WoT = WTqkv + 3072 * 1024;                   // 1024*1024
  __bf16* Xb = WoT + 1024 * 1024;                      // 4096*1024
  __bf16* Qb = Xb + (size_t)S_LEN * DMODEL;
  __bf16* Kb = Qb + (size_t)NH * S_LEN * HDIM;
  __bf16* Vb = Kb + (size_t)NH * S_LEN * HDIM;
  __bf16* Vtb = Vb + (size_t)NH * S_LEN * HDIM;
  __bf16* AO = Vb;  // V raw is dead after V->Vt transpose

  convert_f32_bf16<<<dim3(S_LEN * DMODEL / 1024), 256, 0, stream>>>(X, Xb);

  transpose_tiles<float><<<dim3(16, 16, 1), 256, 0, stream>>>(wq, WTqkv, 1024, 1024);
  transpose_tiles<float><<<dim3(16, 16, 1), 256, 0, stream>>>(wk, WTqkv + 1024 * 1024, 1024, 1024);
  transpose_tiles<float><<<dim3(16, 16, 1), 256, 0, stream>>>(wv, WTqkv + 2 * 1024 * 1024, 1024, 1024);
  transpose_tiles<float><<<dim3(16, 16, 1), 256, 0, stream>>>(wo, WoT, 1024, 1024);

  gemm_bt<1><<<dim3(32, 24), 256, 0, stream>>>(Xb, WTqkv, Qb, Kb, Vb, nullptr, 1024, 3072);

  rope_kernel<<<dim3((NH * S_LEN * 32) / 256), 256, 0, stream>>>(Qb, Kb, freqs);

  transpose_tiles<__bf16><<<dim3(1, 64, NH), 256, 0, stream>>>(Vb, Vtb, S_LEN, HDIM);

  attn_kernel<<<dim3(512), 256, 0, stream>>>(Qb, Kb, Vtb, mask, AO);

  gemm_bt<0><<<dim3(32, 8), 256, 0, stream>>>(AO, WoT, nullptr, nullptr, nullptr, out, 1024, 1024);
}

// Round 8
// 229.960 us; speedup vs baseline: 1.6304x; 1.4347x over previous
//
#include <hip/hip_runtime.h>
#include <stdint.h>

#define S_LEN 4096
#define DMODEL 1024
#define NH 16
#define HDIM 64
#define LOG2E 1.44269504088896340736f

typedef __attribute__((ext_vector_type(8))) __bf16 bf16x8;
typedef __attribute__((ext_vector_type(4))) __bf16 bf16x4;
typedef __attribute__((ext_vector_type(2))) __bf16 bf16x2;
typedef __attribute__((ext_vector_type(4))) float f32x4;
typedef __attribute__((ext_vector_type(16))) float f32x16;
typedef __attribute__((ext_vector_type(4))) unsigned int uint32x4;

// ---------------- f32 -> bf16 pack (vectorized) -------------------------------
__global__ __launch_bounds__(256) void convert_f32_bf16(const float* __restrict__ src,
                                                        __bf16* __restrict__ dst) {
  int idx = blockIdx.x * 256 + threadIdx.x;
  f32x4 v = ((const f32x4*)src)[idx];
  bf16x4 o;
#pragma unroll
  for (int i = 0; i < 4; ++i) o[i] = (__bf16)v[i];
  ((bf16x4*)dst)[idx] = o;
}

// ---------------- tiled transpose (64x64 tiles, batched via z) ----------------
template <typename T>
__global__ __launch_bounds__(256) void transpose_tiles(const T* __restrict__ src,
                                                       __bf16* __restrict__ dst,
                                                       int R, int C) {
  src += (size_t)blockIdx.z * R * C;
  dst += (size_t)blockIdx.z * R * C;
  __shared__ __bf16 tile[64][65];
  const int r0 = blockIdx.y * 64, c0 = blockIdx.x * 64;
  const int t = threadIdx.x;
  const int col = t & 63, rsub = t >> 6;
#pragma unroll
  for (int i = 0; i < 16; ++i) {
    int r = rsub + i * 4;
    tile[r][col] = (__bf16)src[(size_t)(r0 + r) * C + (c0 + col)];
  }
  __syncthreads();
#pragma unroll
  for (int i = 0; i < 16; ++i) {
    int r = rsub + i * 4;
    dst[(size_t)(c0 + r) * R + (r0 + col)] = tile[col][r];
  }
}

// ---------------- GEMM: C = A (M x K) * BT^T, BT is (N x K) row-major ---------
template <int EPI>
__global__ __launch_bounds__(256) void gemm_bt(const __bf16* __restrict__ A,
                                               const __bf16* __restrict__ BT,
                                               __bf16* __restrict__ Cq,
                                               __bf16* __restrict__ Ck,
                                               __bf16* __restrict__ Cv,
                                               float* __restrict__ Cout,
                                               int Kdim, int Ndim) {
  __shared__ __align__(16) __bf16 At[128][40];
  __shared__ __align__(16) __bf16 Bt[128][40];
  const int t = threadIdx.x;
  const int wave = t >> 6, lane = t & 63;
  const int wr = wave >> 1, wc = wave & 1;
  const int lrow = lane & 15, lk = lane >> 4;
  const int bm = blockIdx.x, bn = blockIdx.y;

  f32x4 acc[4][4];
#pragma unroll
  for (int i = 0; i < 4; ++i)
#pragma unroll
    for (int j = 0; j < 4; ++j) acc[i][j] = f32x4{0.f, 0.f, 0.f, 0.f};

  const int arow0 = bm * 128, brow0 = bn * 128;
  for (int k0 = 0; k0 < Kdim; k0 += 32) {
    __syncthreads();
#pragma unroll
    for (int u = 0; u < 2; ++u) {
      int idx = t + u * 256;
      int row = idx >> 2, col = (idx & 3) * 8;
      *(bf16x8*)&At[row][col] =
          *(const bf16x8*)&A[(size_t)(arow0 + row) * Kdim + (k0 + col)];
      *(bf16x8*)&Bt[row][col] =
          *(const bf16x8*)&BT[(size_t)(brow0 + row) * Kdim + (k0 + col)];
    }
    __syncthreads();
    bf16x8 af[4], bfr[4];
#pragma unroll
    for (int mi = 0; mi < 4; ++mi)
      af[mi] = *(const bf16x8*)&At[wr * 64 + mi * 16 + lrow][lk * 8];
#pragma unroll
    for (int ni = 0; ni < 4; ++ni)
      bfr[ni] = *(const bf16x8*)&Bt[wc * 64 + ni * 16 + lrow][lk * 8];
#pragma unroll
    for (int mi = 0; mi < 4; ++mi)
#pragma unroll
      for (int ni = 0; ni < 4; ++ni)
        acc[mi][ni] =
            __builtin_amdgcn_mfma_f32_16x16x32_bf16(af[mi], bfr[ni], acc[mi][ni], 0, 0, 0);
  }

  const int rb = bm * 128 + wr * 64 + lk * 4;
  const int cb = bn * 128 + wc * 64 + lrow;
#pragma unroll
  for (int mi = 0; mi < 4; ++mi)
#pragma unroll
    for (int ni = 0; ni < 4; ++ni) {
      int c = cb + ni * 16;
#pragma unroll
      for (int r = 0; r < 4; ++r) {
        int row = rb + mi * 16 + r;
        float v = acc[mi][ni][r];
        if (EPI == 0) {
          Cout[(size_t)row * Ndim + c] = v;
        } else {
          int type = c >> 10, d = c & 1023;
          int hh = d >> 6, hd = d & 63;
          __bf16* dp = (type == 0) ? Cq : (type == 1) ? Ck : Cv;
          dp[((size_t)hh * S_LEN + row) * HDIM + hd] = (__bf16)v;
        }
      }
    }
}

// ---------------- RoPE in place on (NH, S, HD) Q and K ------------------------
__global__ __launch_bounds__(256) void rope_kernel(__bf16* __restrict__ Q,
                                                   __bf16* __restrict__ Kb,
                                                   const float* __restrict__ freqs) {
  size_t idx = (size_t)blockIdx.x * 256 + threadIdx.x;
  int i = idx & 31;
  size_t rest = idx >> 5;
  int s = rest & 4095;
  int h = (int)(rest >> 12);
  float c = freqs[(s * 32 + i) * 2 + 0];
  float sn = freqs[(s * 32 + i) * 2 + 1];
  size_t base = ((size_t)h * S_LEN + s) * HDIM + 2 * i;
  float qa = (float)Q[base], qb = (float)Q[base + 1];
  Q[base] = (__bf16)(qa * c - qb * sn);
  Q[base + 1] = (__bf16)(qa * sn + qb * c);
  float ka = (float)Kb[base], kb2 = (float)Kb[base + 1];
  Kb[base] = (__bf16)(ka * c - kb2 * sn);
  Kb[base + 1] = (__bf16)(ka * sn + kb2 * c);
}

// ---------------- flash attention: 8 waves, LDS-staged K/V (XOR-swizzled), ----
// async-stage split, swapped-QK^T 32x32x16, in-register softmax.
// grid = 256 blocks (16 qb x 16 heads), 512 threads. Per 64-key tile:
//   issue global K/V(t+1) -> compute tile t from LDS -> ds_write(t+1) -> barrier
__global__ __launch_bounds__(512, 2) void attn_kernel(const __bf16* __restrict__ Q,
                                                      const __bf16* __restrict__ Kmat,
                                                      const __bf16* __restrict__ Vt,
                                                      const float* __restrict__ mask,
                                                      __bf16* __restrict__ AO) {
  __shared__ float maskL[S_LEN];                       // 16 KB, log2-domain mask add
  __shared__ __align__(16) __bf16 Kl[2][64][64];       // [buf][key][d], 128B rows
  __shared__ __align__(16) __bf16 Vl[2][64][64];       // [buf][d][key], 128B rows

  const int t = threadIdx.x;                    // 0..511
  const int id = blockIdx.x;                    // 0..255
  const int swz = (id & 7) * 32 + (id >> 3);    // bijective 256 = 8*32, 2 heads/XCD
  const int h = swz >> 4;
  const int qb = swz & 15;
  const int wave = t >> 6, lane = t & 63;
  const int lq = lane & 31, hi = lane >> 5;
  const int sw = lq & 7;                        // read-side swizzle bits

  const __bf16* Kh = Kmat + (size_t)h * S_LEN * HDIM;
  const __bf16* Vh = Vt + (size_t)h * HDIM * S_LEN;

  // staging coords: thread stages 16B of K and 16B of V per tile
  const int sr = t >> 3;                        // row 0..63
  const int sc = t & 7;                         // 16B segment 0..7
  const int scs = (sc ^ (sr & 7)) * 8;          // write-side swizzled elem offset
  const __bf16* Kgb = Kh + (size_t)sr * HDIM + sc * 8;   // + kb*HDIM per tile
  const __bf16* Vgb = Vh + (size_t)sr * S_LEN + sc * 8;  // + kb per tile

  // ---- prologue: mask (log2 domain) + tile 0 staged
  uint32x4 kreg, vreg;
#pragma unroll
  for (int i = 0; i < 8; ++i) {
    int idx = t + i * 512;
    maskL[idx] = (1.0f - mask[idx]) * (-10000.0f * LOG2E);
  }
  kreg = *(const uint32x4*)(Kgb);
  vreg = *(const uint32x4*)(Vgb);
  *(uint32x4*)&Kl[0][sr][scs] = kreg;
  *(uint32x4*)&Vl[0][sr][scs] = vreg;

  // Q fragments (B-operand), UNSCALED (scale folded into post-MFMA FMA)
  const __bf16* Qh = Q + ((size_t)h * S_LEN + qb * 256 + wave * 32 + lq) * HDIM;
  bf16x8 qf[4];
#pragma unroll
  for (int ds = 0; ds < 4; ++ds) qf[ds] = *(const bf16x8*)(Qh + ds * 16 + hi * 8);

  __syncthreads();

  const float SCL = 0.125f * LOG2E;
  float m = -1e30f, l = 0.f;
  f32x16 o0, o1;
#pragma unroll
  for (int r = 0; r < 16; ++r) { o0[r] = 0.f; o1[r] = 0.f; }

  for (int it = 0; it < S_LEN / 64; ++it) {
    const int cur = it & 1;
    const int kb = it * 64;

    // ---- issue next tile's global loads (latency hides under this tile's compute)
    if (it < S_LEN / 64 - 1) {
      kreg = *(const uint32x4*)(Kgb + (size_t)(kb + 64) * HDIM);
      vreg = *(const uint32x4*)(Vgb + (kb + 64));
    }

    // ---- QK^T swapped: p[r] = S_raw[k = kb + (r&3)+8*(r>>2)+4*hi][q = lq]
    f32x16 p0, p1;
#pragma unroll
    for (int r = 0; r < 16; ++r) { p0[r] = 0.f; p1[r] = 0.f; }
#pragma unroll
    for (int ds = 0; ds < 4; ++ds) {
      int sg = ((ds << 1) | hi) ^ sw;
      bf16x8 kf0 = *(const bf16x8*)&Kl[cur][lq][sg * 8];
      p0 = __builtin_amdgcn_mfma_f32_32x32x16_bf16(kf0, qf[ds], p0, 0, 0, 0);
    }
#pragma unroll
    for (int ds = 0; ds < 4; ++ds) {
      int sg = ((ds << 1) | hi) ^ sw;
      bf16x8 kf1 = *(const bf16x8*)&Kl[cur][lq + 32][sg * 8];
      p1 = __builtin_amdgcn_mfma_f32_32x32x16_bf16(kf1, qf[ds], p1, 0, 0, 0);
    }

    // ---- fused scale+mask: p = S_raw*(0.125*log2e) + mask_log2
#pragma unroll
    for (int tq = 0; tq < 4; ++tq) {
      f32x4 ma0 = *(const f32x4*)&maskL[kb + tq * 8 + hi * 4];
      f32x4 ma1 = *(const f32x4*)&maskL[kb + 32 + tq * 8 + hi * 4];
#pragma unroll
      for (int c = 0; c < 4; ++c) {
        p0[tq * 4 + c] = fmaf(p0[tq * 4 + c], SCL, ma0[c]);
        p1[tq * 4 + c] = fmaf(p1[tq * 4 + c], SCL, ma1[c]);
      }
    }

    // ---- tree max over 32 vals + one xor-32 shuffle
    float mA, mB;
    {
      float u0 = fmaxf(fmaxf(p0[0], p0[1]), fmaxf(p0[2], p0[3]));
      float u1 = fmaxf(fmaxf(p0[4], p0[5]), fmaxf(p0[6], p0[7]));
      float u2 = fmaxf(fmaxf(p0[8], p0[9]), fmaxf(p0[10], p0[11]));
      float u3 = fmaxf(fmaxf(p0[12], p0[13]), fmaxf(p0[14], p0[15]));
      mA = fmaxf(fmaxf(u0, u1), fmaxf(u2, u3));
      float w0 = fmaxf(fmaxf(p1[0], p1[1]), fmaxf(p1[2], p1[3]));
      float w1 = fmaxf(fmaxf(p1[4], p1[5]), fmaxf(p1[6], p1[7]));
      float w2 = fmaxf(fmaxf(p1[8], p1[9]), fmaxf(p1[10], p1[11]));
      float w3 = fmaxf(fmaxf(p1[12], p1[13]), fmaxf(p1[14], p1[15]));
      mB = fmaxf(fmaxf(w0, w1), fmaxf(w2, w3));
    }
    float mx = fmaxf(mA, mB);
    mx = fmaxf(mx, __shfl_xor(mx, 32));

    // ---- defer-rescale (skip O-rescale when max didn't grow)
    if (!__all(mx <= m)) {
      float mn = fmaxf(m, mx);
      float al = exp2f(m - mn);
      m = mn;
      l *= al;
#pragma unroll
      for (int r = 0; r < 16; ++r) { o0[r] *= al; o1[r] *= al; }
    }

    // ---- exp (log2 domain) + tree sum
#pragma unroll
    for (int r = 0; r < 16; ++r) p0[r] = exp2f(p0[r] - m);
#pragma unroll
    for (int r = 0; r < 16; ++r) p1[r] = exp2f(p1[r] - m);
    {
      float a0 = (p0[0] + p0[1]) + (p0[2] + p0[3]);
      float a1 = (p0[4] + p0[5]) + (p0[6] + p0[7]);
      float a2 = (p0[8] + p0[9]) + (p0[10] + p0[11]);
      float a3 = (p0[12] + p0[13]) + (p0[14] + p0[15]);
      float b0 = (p1[0] + p1[1]) + (p1[2] + p1[3]);
      float b1 = (p1[4] + p1[5]) + (p1[6] + p1[7]);
      float b2 = (p1[8] + p1[9]) + (p1[10] + p1[11]);
      float b3 = (p1[12] + p1[13]) + (p1[14] + p1[15]);
      float ps = ((a0 + a1) + (a2 + a3)) + ((b0 + b1) + (b2 + b3));
      ps += __shfl_xor(ps, 32);
      l += ps;
    }

    // ---- pack P to bf16 pairs: tt[tp] holds k = 8*(tp>>1) + 4*hi + (2tp&3)+{0,1}
    unsigned int tt0[8], tt1[8];
#pragma unroll
    for (int tp = 0; tp < 8; ++tp) {
      bf16x2 w0, w1;
      w0[0] = (__bf16)p0[2 * tp]; w0[1] = (__bf16)p0[2 * tp + 1];
      w1[0] = (__bf16)p1[2 * tp]; w1[1] = (__bf16)p1[2 * tp + 1];
      tt0[tp] = __builtin_bit_cast(unsigned int, w0);
      tt1[tp] = __builtin_bit_cast(unsigned int, w1);
    }

    // ---- PV with B-fragments built via shfl_xor(32)+select (verified round 5)
#pragma unroll
    for (int ks = 0; ks < 4; ++ks) {
      unsigned int b0, b1, b2, b3;
      if (ks == 0)      { b0 = tt0[0]; b1 = tt0[1]; b2 = tt0[2]; b3 = tt0[3]; }
      else if (ks == 1) { b0 = tt0[4]; b1 = tt0[5]; b2 = tt0[6]; b3 = tt0[7]; }
      else if (ks == 2) { b0 = tt1[0]; b1 = tt1[1]; b2 = tt1[2]; b3 = tt1[3]; }
      else              { b0 = tt1[4]; b1 = tt1[5]; b2 = tt1[6]; b3 = tt1[7]; }
      unsigned int x0 = (unsigned int)__shfl_xor((int)b0, 32);
      unsigned int x1 = (unsigned int)__shfl_xor((int)b1, 32);
      unsigned int x2 = (unsigned int)__shfl_xor((int)b2, 32);
      unsigned int x3 = (unsigned int)__shfl_xor((int)b3, 32);
      uint32x4 pb;
      pb[0] = hi ? x2 : b0;
      pb[1] = hi ? x3 : b1;
      pb[2] = hi ? b2 : x0;
      pb[3] = hi ? b3 : x1;
      bf16x8 pbv = __builtin_bit_cast(bf16x8, pb);
      int sg = ((ks << 1) | hi) ^ sw;
      bf16x8 v0 = *(const bf16x8*)&Vl[cur][lq][sg * 8];
      bf16x8 v1 = *(const bf16x8*)&Vl[cur][lq + 32][sg * 8];
      o0 = __builtin_amdgcn_mfma_f32_32x32x16_bf16(v0, pbv, o0, 0, 0, 0);
      o1 = __builtin_amdgcn_mfma_f32_32x32x16_bf16(v1, pbv, o1, 0, 0, 0);
    }

    // ---- write next tile into the other buffer, then sync
    if (it < S_LEN / 64 - 1) {
      *(uint32x4*)&Kl[cur ^ 1][sr][scs] = kreg;
      *(uint32x4*)&Vl[cur ^ 1][sr][scs] = vreg;
      __syncthreads();
    }
  }

  // ---- epilogue: normalize and store; d = 8*tq + 4*hi + c, q = lq
  float inv = 1.0f / fmaxf(l, 1e-30f);
  __bf16* aorow = AO + (size_t)(qb * 256 + wave * 32 + lq) * DMODEL + h * HDIM;
#pragma unroll
  for (int tq = 0; tq < 4; ++tq) {
    bf16x4 ov0, ov1;
#pragma unroll
    for (int c = 0; c < 4; ++c) {
      ov0[c] = (__bf16)(o0[tq * 4 + c] * inv);
      ov1[c] = (__bf16)(o1[tq * 4 + c] * inv);
    }
    *(bf16x4*)(aorow + tq * 8 + hi * 4) = ov0;
    *(bf16x4*)(aorow + 32 + tq * 8 + hi * 4) = ov1;
  }
}

// ------------------------------------------------------------------------------
extern "C" void kernel_launch(void* const* d_in, const int* in_sizes, int n_in,
                              void* d_out, int out_size, void* d_ws, size_t ws_size,
                              hipStream_t stream) {
  const float* X = (const float*)d_in[0];
  const float* freqs = (const float*)d_in[1];
  const float* mask = (const float*)d_in[2];
  const float* wq = (const float*)d_in[3];
  const float* wk = (const float*)d_in[4];
  const float* wv = (const float*)d_in[5];
  const float* wo = (const float*)d_in[6];
  float* out = (float*)d_out;

  __bf16* WTqkv = (__bf16*)d_ws;                       // 3072*1024
  __bf16* WoT = WTqkv + 3072 * 1024;                   // 1024*1024
  __bf16* Xb = WoT + 1024 * 1024;                      // 4096*1024
  __bf16* Qb = Xb + (size_t)S_LEN * DMODEL;
  __bf16* Kb = Qb + (size_t)NH * S_LEN * HDIM;
  __bf16* Vb = Kb + (size_t)NH * S_LEN * HDIM;
  __bf16* Vtb = Vb + (size_t)NH * S_LEN * HDIM;
  __bf16* AO = Vb;  // V raw is dead after V->Vt transpose

  convert_f32_bf16<<<dim3(S_LEN * DMODEL / 1024), 256, 0, stream>>>(X, Xb);

  transpose_tiles<float><<<dim3(16, 16, 1), 256, 0, stream>>>(wq, WTqkv, 1024, 1024);
  transpose_tiles<float><<<dim3(16, 16, 1), 256, 0, stream>>>(wk, WTqkv + 1024 * 1024, 1024, 1024);
  transpose_tiles<float><<<dim3(16, 16, 1), 256, 0, stream>>>(wv, WTqkv + 2 * 1024 * 1024, 1024, 1024);
  transpose_tiles<float><<<dim3(16, 16, 1), 256, 0, stream>>>(wo, WoT, 1024, 1024);

  gemm_bt<1><<<dim3(32, 24), 256, 0, stream>>>(Xb, WTqkv, Qb, Kb, Vb, nullptr, 1024, 3072);

  rope_kernel<<<dim3((NH * S_LEN * 32) / 256), 256, 0, stream>>>(Qb, Kb, freqs);

  transpose_tiles<__bf16><<<dim3(1, 64, NH), 256, 0, stream>>>(Vb, Vtb, S_LEN, HDIM);

  attn_kernel<<<dim3(256), 512, 0, stream>>>(Qb, Kb, Vtb, mask, AO);

  gemm_bt<0><<<dim3(32, 8), 256, 0, stream>>>(AO, WoT, nullptr, nullptr, nullptr, out, 1024, 1024);
}